// Round 14
// baseline (378.555 us; speedup 1.0000x reference)
//
#include <hip/hip_runtime.h>
#include <hip/hip_bf16.h>
#include <hip/hip_fp16.h>

typedef __attribute__((ext_vector_type(8))) short short8;
typedef __attribute__((ext_vector_type(4))) float f32x4;
typedef __attribute__((ext_vector_type(4))) unsigned short us4;

#define MFMA16(a, b, c) __builtin_amdgcn_mfma_f32_16x16x32_bf16(a, b, c, 0, 0, 0)
#define LN100 4.605170185988091f

__device__ __forceinline__ short f2bf(float f) {
    unsigned u = __float_as_uint(f);
    unsigned r = (u + 0x7fffu + ((u >> 16) & 1u)) >> 16;
    return (short)r;
}
__device__ __forceinline__ float h2f(unsigned short u) {
    __half_raw r; r.x = u;
    return __half2float(__half(r));
}

// ---------------- prep kernels ----------------

// Writes weight images PRE-SWIZZLED into the exact LDS byte layout k_fused stages:
// qkv: per 64-col tile nt, L = r*192 + (((k>>3)^(r&7))<<3) + (k&7), r = col%64.
// proj: L = r*192 + (((k>>3)^(r&7))<<3) + (k&7), r = out-col (0..191).
__global__ __launch_bounds__(256) void k_wcvt(const float* qkv_w, const float* proj_w,
                                              short* wq_sw, short* wp_sw) {
    int i = blockIdx.x * 256 + threadIdx.x;
    if (i < 576 * 192) {
        int c = i / 192, k = i % 192;
        int nt = c >> 6, r = c & 63;
        int L = nt * 12288 + r * 192 + ((((k >> 3) ^ (r & 7)) << 3) | (k & 7));
        wq_sw[L] = f2bf(qkv_w[i]);
    } else {
        int j = i - 576 * 192;
        if (j < 192 * 192) {
            int r = j / 192, k = j % 192;
            int L = r * 192 + ((((k >> 3) ^ (r & 7)) << 3) | (k & 7));
            wp_sw[L] = f2bf(proj_w[j]);
        }
    }
}

// cpb MLP: 507 entries, 3 -> 512 relu -> 6
__global__ __launch_bounds__(64) void k_tbl(const float* tab, const float* w1, const float* b1,
                                            const float* w2, float* tbl) {
    int e = blockIdx.x;
    int t = threadIdx.x;
    float c0 = tab[e * 3 + 0], c1 = tab[e * 3 + 1], c2 = tab[e * 3 + 2];
    float acc[6] = {0.f, 0.f, 0.f, 0.f, 0.f, 0.f};
    for (int u = t; u < 512; u += 64) {
        float hv = c0 * w1[u * 3 + 0] + c1 * w1[u * 3 + 1] + c2 * w1[u * 3 + 2] + b1[u];
        hv = fmaxf(hv, 0.f);
        #pragma unroll
        for (int hh = 0; hh < 6; ++hh) acc[hh] += hv * w2[hh * 512 + u];
    }
    #pragma unroll
    for (int hh = 0; hh < 6; ++hh) {
        float v = acc[hh];
        for (int off = 32; off > 0; off >>= 1) v += __shfl_xor(v, off, 64);
        if (t == 0) tbl[e * 6 + hh] = v;
    }
}

// bm[w][h][q][k112] = 16*sigmoid(cpb) + mask (fp16), -60000 for k>=98
__global__ __launch_bounds__(256) void k_bm(const float* tbl, const int* rpi, const float* mask,
                                            __half* bm) {
    int i = blockIdx.x * 256 + threadIdx.x;
    if (i >= 64 * 6 * 98 * 112) return;
    int k = i % 112;
    int q = (i / 112) % 98;
    int h = (i / (112 * 98)) % 6;
    int w = i / (112 * 98 * 6);
    float v;
    if (k < 98) {
        float t = tbl[rpi[q * 98 + k] * 6 + h];
        v = 16.f / (1.f + expf(-t)) + mask[(w * 98 + q) * 98 + k];
    } else v = -60000.f;
    bm[i] = __float2half(v);
}

// ---------------- fully fused kernel: one block per window, 14 waves ----------------
// LDS (shorts): Qs[112][192]@0, Ks[112][192]@21504, VT 6x[32][128]@43008 (ao
// overlay 6x[112][32]), Bs[64][192]@67584.  XOR chunk swizzle: chunk^=(row&7).
// Wave (rg,hf): rg=wv>>1 owns rows rg*16..+16; hf=wv&1 splits cols/heads.
// Weight staging is LINEAR (images pre-swizzled by k_wcvt); read side unchanged.
__global__ __launch_bounds__(896) void k_fused(const float* x, const short* wq, const float* qkv_b,
                                               const float* lsc, const short* wp, const float* proj_b,
                                               const __half* bm, float* outp) {
    __shared__ short lds[79872];
    short* Qs = lds;
    short* Ks = lds + 21504;
    short* VT = lds + 43008;
    short* Bs = lds + 67584;

    const int tid = threadIdx.x;
    const int wv = tid >> 6;
    const int lane = tid & 63;
    const int l16 = lane & 15, q4 = lane >> 4;
    const int rg = wv >> 1;
    const int hf = wv & 1;
    const int b = blockIdx.x;
    const int w = b & 63;
    const f32x4 zz = {0.f, 0.f, 0.f, 0.f};

    // zero VT (incl. token pad 98..127)
    {
        short8 z = {0, 0, 0, 0, 0, 0, 0, 0};
        #pragma unroll
        for (int it = 0; it < 4; ++it) {
            int c = tid + it * 896;
            if (c < 3072) *(short8*)&VT[c * 8] = z;
        }
    }
    // x A-frags: 16 rows per row-group, K=192, fp32->bf16 in-register
    short8 af[6];
    {
        int arow = rg * 16 + l16; if (arow > 97) arow = 97;
        const float* xp = x + ((size_t)b * 98 + arow) * 192 + q4 * 8;
        #pragma unroll
        for (int ks = 0; ks < 6; ++ks) {
            float4 f0 = *(const float4*)(xp + ks * 32);
            float4 f1 = *(const float4*)(xp + ks * 32 + 4);
            union { int i4[4]; short8 s; } u;
            asm("v_cvt_pk_bf16_f32 %0, %1, %2" : "=v"(u.i4[0]) : "v"(f0.x), "v"(f0.y));
            asm("v_cvt_pk_bf16_f32 %0, %1, %2" : "=v"(u.i4[1]) : "v"(f0.z), "v"(f0.w));
            asm("v_cvt_pk_bf16_f32 %0, %1, %2" : "=v"(u.i4[2]) : "v"(f1.x), "v"(f1.y));
            asm("v_cvt_pk_bf16_f32 %0, %1, %2" : "=v"(u.i4[3]) : "v"(f1.z), "v"(f1.w));
            af[ks] = u.s;
        }
    }
    // prologue: stage B tile 0 (1536 short8 chunks over 896 threads), LINEAR copy
    short8 t0, t1;
    {
        t0 = *(const short8*)(wq + tid * 8);
        if (tid < 640) t1 = *(const short8*)(wq + (tid + 896) * 8);
    }
    __syncthreads();   // VT zeros visible before any VT write
    {
        *(short8*)&Bs[tid * 8] = t0;
        if (tid < 640) *(short8*)&Bs[(tid + 896) * 8] = t1;
    }
    __syncthreads();

    const int row_w = rg * 16 + q4 * 4;
    // ---- qkv GEMM: 9 col-tiles of 64; wave does 16 rows x 32 cols (hf half) ----
    #pragma unroll 1
    for (int nt = 0; nt < 9; ++nt) {
        if (nt < 8) {   // T14: issue next tile's loads before compute (linear image copy)
            const short* wn = wq + (nt + 1) * 12288;
            t0 = *(const short8*)(wn + tid * 8);
            if (tid < 640) t1 = *(const short8*)(wn + (tid + 896) * 8);
        }
        f32x4 acc[2] = {zz, zz};
        #pragma unroll
        for (int ks = 0; ks < 6; ++ks)
            #pragma unroll
            for (int cf = 0; cf < 2; ++cf) {
                short8 bf = *(const short8*)&Bs[((hf * 2 + cf) * 16 + l16) * 192 +
                                                (((ks * 4 + q4) ^ (l16 & 7)) << 3)];
                acc[cf] = MFMA16(af[ks], bf, acc[cf]);
            }
        {
            int slot = nt * 2 + hf;
            int which = slot / 6;
            int h = slot - which * 6;
            float bia0 = qkv_b[slot * 32 + l16];
            float bia1 = qkv_b[slot * 32 + 16 + l16];
            float sc = 1.0f;
            if (which == 0) sc = __expf(fminf(lsc[h], LN100));
            #pragma unroll
            for (int i = 0; i < 4; ++i) {
                float v0 = acc[0][i] + bia0;
                float v1 = acc[1][i] + bia1;
                if (which < 2) {
                    float ss = v0 * v0 + v1 * v1;
                    ss += __shfl_xor(ss, 1, 16);
                    ss += __shfl_xor(ss, 2, 16);
                    ss += __shfl_xor(ss, 4, 16);
                    ss += __shfl_xor(ss, 8, 16);
                    float rn = sc / fmaxf(sqrtf(ss), 1e-12f);
                    v0 *= rn; v1 *= rn;
                }
                int row = row_w + i;
                if (which == 2) {
                    int swz = (((row >> 3) ^ (l16 & 7)) << 3) + (row & 7);
                    VT[h * 4096 + l16 * 128 + swz]        = f2bf(v0);
                    VT[h * 4096 + (l16 + 16) * 128 + swz] = f2bf(v1);
                } else {
                    short* T = (which == 0) ? Qs : Ks;
                    int c0i = h * 32 + l16, c1i = c0i + 16;
                    T[row * 192 + (((c0i >> 3) ^ (row & 7)) << 3) + (c0i & 7)] = f2bf(v0);
                    T[row * 192 + (((c1i >> 3) ^ (row & 7)) << 3) + (c1i & 7)] = f2bf(v1);
                }
            }
        }
        __syncthreads();
        if (nt < 8) {
            *(short8*)&Bs[tid * 8] = t0;
            if (tid < 640) *(short8*)&Bs[(tid + 896) * 8] = t1;
            __syncthreads();
        }
    }

    // ---- attention: 3 heads per wave (hf*3 .. hf*3+2), 16 q-rows ----
    const int rq = rg * 16 + l16;
    const int qc = rq < 98 ? rq : 97;
    const int srcA = ((q4 & 1) * 2) * 16 + l16;
    const int srcB = srcA + 16;
    const bool hi = (q4 & 2) != 0;

    #pragma unroll 1
    for (int j = 0; j < 3; ++j) {
        const int h = hf * 3 + j;
        const __half* bmp = bm + (((size_t)w * 6 + h) * 98 + qc) * 112;
        us4 bh[7];
        #pragma unroll
        for (int ct = 0; ct < 7; ++ct) bh[ct] = *(const us4*)(bmp + ct * 16 + q4 * 4);
        short8 qf = *(const short8*)&Qs[rq * 192 + (((h * 4 + q4) ^ (l16 & 7)) << 3)];
        f32x4 cc[7];
        #pragma unroll
        for (int ct = 0; ct < 7; ++ct) {
            int rk = ct * 16 + l16;
            short8 kf = *(const short8*)&Ks[rk * 192 + (((h * 4 + q4) ^ (l16 & 7)) << 3)];
            cc[ct] = MFMA16(kf, qf, zz);
        }
        float mx = -1e30f;
        #pragma unroll
        for (int ct = 0; ct < 7; ++ct)
            #pragma unroll
            for (int i = 0; i < 4; ++i) {
                float s = cc[ct][i] + h2f(bh[ct][i]);
                cc[ct][i] = s;
                mx = fmaxf(mx, s);
            }
        mx = fmaxf(mx, __shfl_xor(mx, 16, 64));
        mx = fmaxf(mx, __shfl_xor(mx, 32, 64));
        float sm = 0.f;
        #pragma unroll
        for (int ct = 0; ct < 7; ++ct)
            #pragma unroll
            for (int i = 0; i < 4; ++i) {
                float e = __expf(cc[ct][i] - mx);
                cc[ct][i] = e;
                sm += e;
            }
        sm += __shfl_xor(sm, 16, 64);
        sm += __shfl_xor(sm, 32, 64);
        float ri = 1.f / sm;
        int W[8][2];
        W[7][0] = 0; W[7][1] = 0;
        #pragma unroll
        for (int ct = 0; ct < 7; ++ct) {
            float a0 = cc[ct][0] * ri, a1 = cc[ct][1] * ri;
            float a2 = cc[ct][2] * ri, a3 = cc[ct][3] * ri;
            asm("v_cvt_pk_bf16_f32 %0, %1, %2" : "=v"(W[ct][0]) : "v"(a0), "v"(a1));
            asm("v_cvt_pk_bf16_f32 %0, %1, %2" : "=v"(W[ct][1]) : "v"(a2), "v"(a3));
        }
        f32x4 o0 = zz, o1 = zz;
        #pragma unroll
        for (int km = 0; km < 4; ++km) {
            int A0 = __shfl(W[2 * km][0], srcA, 64), B0 = __shfl(W[2 * km + 1][0], srcA, 64);
            int A1 = __shfl(W[2 * km][1], srcA, 64), B1 = __shfl(W[2 * km + 1][1], srcA, 64);
            int A2 = __shfl(W[2 * km][0], srcB, 64), B2 = __shfl(W[2 * km + 1][0], srcB, 64);
            int A3 = __shfl(W[2 * km][1], srcB, 64), B3 = __shfl(W[2 * km + 1][1], srcB, 64);
            union { int i4[4]; short8 s; } ua;
            ua.i4[0] = hi ? B0 : A0;
            ua.i4[1] = hi ? B1 : A1;
            ua.i4[2] = hi ? B2 : A2;
            ua.i4[3] = hi ? B3 : A3;
            int sA = h * 4096 + l16 * 128 + (((km * 4 + q4) ^ (l16 & 7)) << 3);
            short8 bv0 = *(const short8*)&VT[sA];
            short8 bv1 = *(const short8*)&VT[sA + 2048];
            o0 = MFMA16(ua.s, bv0, o0);
            o1 = MFMA16(ua.s, bv1, o1);
        }
        __syncthreads();   // all PV_h reads of VT[h] done before ao overlay
        #pragma unroll
        for (int i = 0; i < 4; ++i) {
            int q = row_w + i;
            VT[h * 4096 + q * 32 + l16]      = f2bf(o0[i]);
            VT[h * 4096 + q * 32 + 16 + l16] = f2bf(o1[i]);
        }
    }

    // ---- proj: stage pw image (linear copy) into Qs/Ks region, A-frags from ao overlay ----
    {
        short8 pwst[6];
        #pragma unroll
        for (int it = 0; it < 6; ++it) {
            int c = tid + it * 896;
            if (c < 4608) pwst[it] = *(const short8*)(wp + c * 8);
        }
        #pragma unroll
        for (int it = 0; it < 6; ++it) {
            int c = tid + it * 896;
            if (c < 4608) *(short8*)&lds[c * 8] = pwst[it];
        }
    }
    __syncthreads();
    {
        short8 pa[6];
        #pragma unroll
        for (int ks = 0; ks < 6; ++ks)
            pa[ks] = *(const short8*)&VT[ks * 4096 + rq * 32 + q4 * 8];
        f32x4 pacc[6] = {zz, zz, zz, zz, zz, zz};
        #pragma unroll
        for (int ks = 0; ks < 6; ++ks)
            #pragma unroll
            for (int cf = 0; cf < 6; ++cf) {
                short8 bf = *(const short8*)&lds[((hf * 6 + cf) * 16 + l16) * 192 +
                                                 (((ks * 4 + q4) ^ (l16 & 7)) << 3)];
                pacc[cf] = MFMA16(pa[ks], bf, pacc[cf]);
            }
        #pragma unroll
        for (int cf = 0; cf < 6; ++cf) {
            int cg = (hf * 6 + cf) * 16 + l16;
            float bia = proj_b[cg];
            #pragma unroll
            for (int i = 0; i < 4; ++i) {
                int q = row_w + i;
                if (q < 98)
                    outp[((size_t)b * 98 + q) * 192 + cg] = pacc[cf][i] + bia;
            }
        }
    }
}

extern "C" void kernel_launch(void* const* d_in, const int* in_sizes, int n_in,
                              void* d_out, int out_size, void* d_ws, size_t ws_size,
                              hipStream_t stream) {
    const float* x    = (const float*)d_in[0];
    const float* mask = (const float*)d_in[1];
    const float* qkvw = (const float*)d_in[2];
    const float* qkvb = (const float*)d_in[3];
    const float* lsc  = (const float*)d_in[4];
    const float* w1   = (const float*)d_in[5];
    const float* b1   = (const float*)d_in[6];
    const float* w2   = (const float*)d_in[7];
    const float* pw   = (const float*)d_in[8];
    const float* pb   = (const float*)d_in[9];
    const float* tab  = (const float*)d_in[10];
    const int*   rpi  = (const int*)d_in[11];

    char* ws = (char*)d_ws;
    short*  wq  = (short*)(ws + 0);          //   221,184 B (9 tile images)
    short*  wp  = (short*)(ws + 221184);     //    73,728 B (proj image)
    float*  tbl = (float*)(ws + 294912);     //    12,288 B
    __half* bm  = (__half*)(ws + 307200);    // 8,429,568 B (fp16 bias+mask)
    float*  outp = (float*)d_out;

    k_wcvt<<<576, 256, 0, stream>>>(qkvw, pw, wq, wp);
    k_tbl<<<507, 64, 0, stream>>>(tab, w1, b1, w2, tbl);
    k_bm<<<16464, 256, 0, stream>>>(tbl, rpi, mask, bm);
    k_fused<<<2048, 896, 0, stream>>>(x, wq, qkvb, lsc, wp, pb, bm, outp);
}

// Round 15
// 353.799 us; speedup vs baseline: 1.0700x; 1.0700x over previous
//
#include <hip/hip_runtime.h>
#include <hip/hip_bf16.h>
#include <hip/hip_fp16.h>

typedef __attribute__((ext_vector_type(8))) short short8;
typedef __attribute__((ext_vector_type(4))) float f32x4;

#define MFMA16(a, b, c) __builtin_amdgcn_mfma_f32_16x16x32_bf16(a, b, c, 0, 0, 0)
#define LN100 4.605170185988091f

__device__ __forceinline__ short f2bf(float f) {
    unsigned u = __float_as_uint(f);
    unsigned r = (u + 0x7fffu + ((u >> 16) & 1u)) >> 16;
    return (short)r;
}

// ---------------- prep kernels ----------------

// Writes weight images PRE-SWIZZLED into the exact LDS byte layout k_fused stages:
// qkv: per 64-col tile nt, L = r*192 + (((k>>3)^(r&7))<<3) + (k&7), r = col%64.
// proj: L = r*192 + (((k>>3)^(r&7))<<3) + (k&7), r = out-col (0..191).
__global__ __launch_bounds__(256) void k_wcvt(const float* qkv_w, const float* proj_w,
                                              short* wq_sw, short* wp_sw) {
    int i = blockIdx.x * 256 + threadIdx.x;
    if (i < 576 * 192) {
        int c = i / 192, k = i % 192;
        int nt = c >> 6, r = c & 63;
        int L = nt * 12288 + r * 192 + ((((k >> 3) ^ (r & 7)) << 3) | (k & 7));
        wq_sw[L] = f2bf(qkv_w[i]);
    } else {
        int j = i - 576 * 192;
        if (j < 192 * 192) {
            int r = j / 192, k = j % 192;
            int L = r * 192 + ((((k >> 3) ^ (r & 7)) << 3) | (k & 7));
            wp_sw[L] = f2bf(proj_w[j]);
        }
    }
}

// cpb MLP: 507 entries, 3 -> 512 relu -> 6
__global__ __launch_bounds__(64) void k_tbl(const float* tab, const float* w1, const float* b1,
                                            const float* w2, float* tbl) {
    int e = blockIdx.x;
    int t = threadIdx.x;
    float c0 = tab[e * 3 + 0], c1 = tab[e * 3 + 1], c2 = tab[e * 3 + 2];
    float acc[6] = {0.f, 0.f, 0.f, 0.f, 0.f, 0.f};
    for (int u = t; u < 512; u += 64) {
        float hv = c0 * w1[u * 3 + 0] + c1 * w1[u * 3 + 1] + c2 * w1[u * 3 + 2] + b1[u];
        hv = fmaxf(hv, 0.f);
        #pragma unroll
        for (int hh = 0; hh < 6; ++hh) acc[hh] += hv * w2[hh * 512 + u];
    }
    #pragma unroll
    for (int hh = 0; hh < 6; ++hh) {
        float v = acc[hh];
        for (int off = 32; off > 0; off >>= 1) v += __shfl_xor(v, off, 64);
        if (t == 0) tbl[e * 6 + hh] = v;
    }
}

// bm[w][h][q][k112] = 16*sigmoid(cpb) + mask (fp32), -60000 for k>=98
__global__ __launch_bounds__(256) void k_bm(const float* tbl, const int* rpi, const float* mask,
                                            float* bm) {
    int i = blockIdx.x * 256 + threadIdx.x;
    if (i >= 64 * 6 * 98 * 112) return;
    int k = i % 112;
    int q = (i / 112) % 98;
    int h = (i / (112 * 98)) % 6;
    int w = i / (112 * 98 * 6);
    float v;
    if (k < 98) {
        float t = tbl[rpi[q * 98 + k] * 6 + h];
        v = 16.f / (1.f + expf(-t)) + mask[(w * 98 + q) * 98 + k];
    } else v = -60000.f;
    bm[i] = v;
}

// ---------------- fully fused kernel: one block per window, 14 waves ----------------
// LDS (shorts): Qs[112][192]@0, Ks[112][192]@21504, VT 6x[32][128]@43008 (ao
// overlay 6x[112][32]), Bs[64][192]@67584.  XOR chunk swizzle: chunk^=(row&7).
// Wave (rg,hf): rg=wv>>1 owns rows rg*16..+16; hf=wv&1 splits cols/heads.
// Weight staging is LINEAR (images pre-swizzled by k_wcvt); read side unchanged.
__global__ __launch_bounds__(896) void k_fused(const float* x, const short* wq, const float* qkv_b,
                                               const float* lsc, const short* wp, const float* proj_b,
                                               const float* bm, float* outp) {
    __shared__ short lds[79872];
    short* Qs = lds;
    short* Ks = lds + 21504;
    short* VT = lds + 43008;
    short* Bs = lds + 67584;

    const int tid = threadIdx.x;
    const int wv = tid >> 6;
    const int lane = tid & 63;
    const int l16 = lane & 15, q4 = lane >> 4;
    const int rg = wv >> 1;
    const int hf = wv & 1;
    const int b = blockIdx.x;
    const int w = b & 63;
    const f32x4 zz = {0.f, 0.f, 0.f, 0.f};

    // zero VT (incl. token pad 98..127)
    {
        short8 z = {0, 0, 0, 0, 0, 0, 0, 0};
        #pragma unroll
        for (int it = 0; it < 4; ++it) {
            int c = tid + it * 896;
            if (c < 3072) *(short8*)&VT[c * 8] = z;
        }
    }
    // x A-frags: 16 rows per row-group, K=192, fp32->bf16 in-register
    short8 af[6];
    {
        int arow = rg * 16 + l16; if (arow > 97) arow = 97;
        const float* xp = x + ((size_t)b * 98 + arow) * 192 + q4 * 8;
        #pragma unroll
        for (int ks = 0; ks < 6; ++ks) {
            float4 f0 = *(const float4*)(xp + ks * 32);
            float4 f1 = *(const float4*)(xp + ks * 32 + 4);
            union { int i4[4]; short8 s; } u;
            asm("v_cvt_pk_bf16_f32 %0, %1, %2" : "=v"(u.i4[0]) : "v"(f0.x), "v"(f0.y));
            asm("v_cvt_pk_bf16_f32 %0, %1, %2" : "=v"(u.i4[1]) : "v"(f0.z), "v"(f0.w));
            asm("v_cvt_pk_bf16_f32 %0, %1, %2" : "=v"(u.i4[2]) : "v"(f1.x), "v"(f1.y));
            asm("v_cvt_pk_bf16_f32 %0, %1, %2" : "=v"(u.i4[3]) : "v"(f1.z), "v"(f1.w));
            af[ks] = u.s;
        }
    }
    // prologue: stage B tile 0 (1536 short8 chunks over 896 threads), LINEAR copy
    short8 t0, t1;
    {
        t0 = *(const short8*)(wq + tid * 8);
        if (tid < 640) t1 = *(const short8*)(wq + (tid + 896) * 8);
    }
    __syncthreads();   // VT zeros visible before any VT write
    {
        *(short8*)&Bs[tid * 8] = t0;
        if (tid < 640) *(short8*)&Bs[(tid + 896) * 8] = t1;
    }
    __syncthreads();

    const int row_w = rg * 16 + q4 * 4;
    // ---- qkv GEMM: 9 col-tiles of 64; wave does 16 rows x 32 cols (hf half) ----
    #pragma unroll 1
    for (int nt = 0; nt < 9; ++nt) {
        if (nt < 8) {   // T14: issue next tile's loads before compute (linear image copy)
            const short* wn = wq + (nt + 1) * 12288;
            t0 = *(const short8*)(wn + tid * 8);
            if (tid < 640) t1 = *(const short8*)(wn + (tid + 896) * 8);
        }
        f32x4 acc[2] = {zz, zz};
        #pragma unroll
        for (int ks = 0; ks < 6; ++ks)
            #pragma unroll
            for (int cf = 0; cf < 2; ++cf) {
                short8 bf = *(const short8*)&Bs[((hf * 2 + cf) * 16 + l16) * 192 +
                                                (((ks * 4 + q4) ^ (l16 & 7)) << 3)];
                acc[cf] = MFMA16(af[ks], bf, acc[cf]);
            }
        {
            int slot = nt * 2 + hf;
            int which = slot / 6;
            int h = slot - which * 6;
            float bia0 = qkv_b[slot * 32 + l16];
            float bia1 = qkv_b[slot * 32 + 16 + l16];
            float sc = 1.0f;
            if (which == 0) sc = __expf(fminf(lsc[h], LN100));
            #pragma unroll
            for (int i = 0; i < 4; ++i) {
                float v0 = acc[0][i] + bia0;
                float v1 = acc[1][i] + bia1;
                if (which < 2) {
                    float ss = v0 * v0 + v1 * v1;
                    ss += __shfl_xor(ss, 1, 16);
                    ss += __shfl_xor(ss, 2, 16);
                    ss += __shfl_xor(ss, 4, 16);
                    ss += __shfl_xor(ss, 8, 16);
                    float rn = sc / fmaxf(sqrtf(ss), 1e-12f);
                    v0 *= rn; v1 *= rn;
                }
                int row = row_w + i;
                if (which == 2) {
                    int swz = (((row >> 3) ^ (l16 & 7)) << 3) + (row & 7);
                    VT[h * 4096 + l16 * 128 + swz]        = f2bf(v0);
                    VT[h * 4096 + (l16 + 16) * 128 + swz] = f2bf(v1);
                } else {
                    short* T = (which == 0) ? Qs : Ks;
                    int c0i = h * 32 + l16, c1i = c0i + 16;
                    T[row * 192 + (((c0i >> 3) ^ (row & 7)) << 3) + (c0i & 7)] = f2bf(v0);
                    T[row * 192 + (((c1i >> 3) ^ (row & 7)) << 3) + (c1i & 7)] = f2bf(v1);
                }
            }
        }
        __syncthreads();
        if (nt < 8) {
            *(short8*)&Bs[tid * 8] = t0;
            if (tid < 640) *(short8*)&Bs[(tid + 896) * 8] = t1;
            __syncthreads();
        }
    }

    // ---- attention: 3 heads per wave (hf*3 .. hf*3+2), 16 q-rows ----
    const int rq = rg * 16 + l16;
    const int qc = rq < 98 ? rq : 97;
    const int srcA = ((q4 & 1) * 2) * 16 + l16;
    const int srcB = srcA + 16;
    const bool hi = (q4 & 2) != 0;

    #pragma unroll 1
    for (int j = 0; j < 3; ++j) {
        const int h = hf * 3 + j;
        const float* bmp = bm + (((size_t)w * 6 + h) * 98 + qc) * 112;
        f32x4 bh[7];
        #pragma unroll
        for (int ct = 0; ct < 7; ++ct) bh[ct] = *(const f32x4*)(bmp + ct * 16 + q4 * 4);
        short8 qf = *(const short8*)&Qs[rq * 192 + (((h * 4 + q4) ^ (l16 & 7)) << 3)];
        f32x4 cc[7];
        #pragma unroll
        for (int ct = 0; ct < 7; ++ct) {
            int rk = ct * 16 + l16;
            short8 kf = *(const short8*)&Ks[rk * 192 + (((h * 4 + q4) ^ (l16 & 7)) << 3)];
            cc[ct] = MFMA16(kf, qf, zz);
        }
        float mx = -1e30f;
        #pragma unroll
        for (int ct = 0; ct < 7; ++ct)
            #pragma unroll
            for (int i = 0; i < 4; ++i) {
                float s = cc[ct][i] + bh[ct][i];
                cc[ct][i] = s;
                mx = fmaxf(mx, s);
            }
        mx = fmaxf(mx, __shfl_xor(mx, 16, 64));
        mx = fmaxf(mx, __shfl_xor(mx, 32, 64));
        float sm = 0.f;
        #pragma unroll
        for (int ct = 0; ct < 7; ++ct)
            #pragma unroll
            for (int i = 0; i < 4; ++i) {
                float e = __expf(cc[ct][i] - mx);
                cc[ct][i] = e;
                sm += e;
            }
        sm += __shfl_xor(sm, 16, 64);
        sm += __shfl_xor(sm, 32, 64);
        float ri = 1.f / sm;
        int W[8][2];
        W[7][0] = 0; W[7][1] = 0;
        #pragma unroll
        for (int ct = 0; ct < 7; ++ct) {
            float a0 = cc[ct][0] * ri, a1 = cc[ct][1] * ri;
            float a2 = cc[ct][2] * ri, a3 = cc[ct][3] * ri;
            asm("v_cvt_pk_bf16_f32 %0, %1, %2" : "=v"(W[ct][0]) : "v"(a0), "v"(a1));
            asm("v_cvt_pk_bf16_f32 %0, %1, %2" : "=v"(W[ct][1]) : "v"(a2), "v"(a3));
        }
        f32x4 o0 = zz, o1 = zz;
        #pragma unroll
        for (int km = 0; km < 4; ++km) {
            int A0 = __shfl(W[2 * km][0], srcA, 64), B0 = __shfl(W[2 * km + 1][0], srcA, 64);
            int A1 = __shfl(W[2 * km][1], srcA, 64), B1 = __shfl(W[2 * km + 1][1], srcA, 64);
            int A2 = __shfl(W[2 * km][0], srcB, 64), B2 = __shfl(W[2 * km + 1][0], srcB, 64);
            int A3 = __shfl(W[2 * km][1], srcB, 64), B3 = __shfl(W[2 * km + 1][1], srcB, 64);
            union { int i4[4]; short8 s; } ua;
            ua.i4[0] = hi ? B0 : A0;
            ua.i4[1] = hi ? B1 : A1;
            ua.i4[2] = hi ? B2 : A2;
            ua.i4[3] = hi ? B3 : A3;
            int sA = h * 4096 + l16 * 128 + (((km * 4 + q4) ^ (l16 & 7)) << 3);
            short8 bv0 = *(const short8*)&VT[sA];
            short8 bv1 = *(const short8*)&VT[sA + 2048];
            o0 = MFMA16(ua.s, bv0, o0);
            o1 = MFMA16(ua.s, bv1, o1);
        }
        __syncthreads();   // all PV_h reads of VT[h] done before ao overlay
        #pragma unroll
        for (int i = 0; i < 4; ++i) {
            int q = row_w + i;
            VT[h * 4096 + q * 32 + l16]      = f2bf(o0[i]);
            VT[h * 4096 + q * 32 + 16 + l16] = f2bf(o1[i]);
        }
    }

    // ---- proj: stage pw image (linear copy) into Qs/Ks region, A-frags from ao overlay ----
    {
        short8 pwst[6];
        #pragma unroll
        for (int it = 0; it < 6; ++it) {
            int c = tid + it * 896;
            if (c < 4608) pwst[it] = *(const short8*)(wp + c * 8);
        }
        #pragma unroll
        for (int it = 0; it < 6; ++it) {
            int c = tid + it * 896;
            if (c < 4608) *(short8*)&lds[c * 8] = pwst[it];
        }
    }
    __syncthreads();
    {
        short8 pa[6];
        #pragma unroll
        for (int ks = 0; ks < 6; ++ks)
            pa[ks] = *(const short8*)&VT[ks * 4096 + rq * 32 + q4 * 8];
        f32x4 pacc[6] = {zz, zz, zz, zz, zz, zz};
        #pragma unroll
        for (int ks = 0; ks < 6; ++ks)
            #pragma unroll
            for (int cf = 0; cf < 6; ++cf) {
                short8 bf = *(const short8*)&lds[((hf * 6 + cf) * 16 + l16) * 192 +
                                                 (((ks * 4 + q4) ^ (l16 & 7)) << 3)];
                pacc[cf] = MFMA16(pa[ks], bf, pacc[cf]);
            }
        #pragma unroll
        for (int cf = 0; cf < 6; ++cf) {
            int cg = (hf * 6 + cf) * 16 + l16;
            float bia = proj_b[cg];
            #pragma unroll
            for (int i = 0; i < 4; ++i) {
                int q = row_w + i;
                if (q < 98)
                    outp[((size_t)b * 98 + q) * 192 + cg] = pacc[cf][i] + bia;
            }
        }
    }
}

extern "C" void kernel_launch(void* const* d_in, const int* in_sizes, int n_in,
                              void* d_out, int out_size, void* d_ws, size_t ws_size,
                              hipStream_t stream) {
    const float* x    = (const float*)d_in[0];
    const float* mask = (const float*)d_in[1];
    const float* qkvw = (const float*)d_in[2];
    const float* qkvb = (const float*)d_in[3];
    const float* lsc  = (const float*)d_in[4];
    const float* w1   = (const float*)d_in[5];
    const float* b1   = (const float*)d_in[6];
    const float* w2   = (const float*)d_in[7];
    const float* pw   = (const float*)d_in[8];
    const float* pb   = (const float*)d_in[9];
    const float* tab  = (const float*)d_in[10];
    const int*   rpi  = (const int*)d_in[11];

    char* ws = (char*)d_ws;
    short*  wq  = (short*)(ws + 0);          //    221,184 B (9 tile images)
    short*  wp  = (short*)(ws + 221184);     //     73,728 B (proj image)
    float*  tbl = (float*)(ws + 294912);     //     12,288 B
    float*  bm  = (float*)(ws + 307200);     // 16,859,136 B (fp32 bias+mask)
    float*  outp = (float*)d_out;

    k_wcvt<<<576, 256, 0, stream>>>(qkvw, pw, wq, wp);
    k_tbl<<<507, 64, 0, stream>>>(tab, w1, b1, w2, tbl);
    k_bm<<<16464, 256, 0, stream>>>(tbl, rpi, mask, bm);
    k_fused<<<2048, 896, 0, stream>>>(x, wq, qkvb, lsc, wp, pb, bm, outp);
}

// Round 17
// 353.628 us; speedup vs baseline: 1.0705x; 1.0005x over previous
//
#include <hip/hip_runtime.h>
#include <hip/hip_bf16.h>
#include <hip/hip_fp16.h>

typedef __attribute__((ext_vector_type(8))) short short8;
typedef __attribute__((ext_vector_type(4))) float f32x4;

#define MFMA16(a, b, c) __builtin_amdgcn_mfma_f32_16x16x32_bf16(a, b, c, 0, 0, 0)
#define LN100 4.605170185988091f

__device__ __forceinline__ short f2bf(float f) {
    unsigned u = __float_as_uint(f);
    unsigned r = (u + 0x7fffu + ((u >> 16) & 1u)) >> 16;
    return (short)r;
}

// ---------------- prep kernels ----------------

// Writes weight images PRE-SWIZZLED into the exact LDS byte layout k_fused stages:
// qkv: per 64-col tile nt, L = r*192 + (((k>>3)^(r&7))<<3) + (k&7), r = col%64.
// proj: L = r*192 + (((k>>3)^(r&7))<<3) + (k&7), r = out-col (0..191).
__global__ __launch_bounds__(256) void k_wcvt(const float* qkv_w, const float* proj_w,
                                              short* wq_sw, short* wp_sw) {
    int i = blockIdx.x * 256 + threadIdx.x;
    if (i < 576 * 192) {
        int c = i / 192, k = i % 192;
        int nt = c >> 6, r = c & 63;
        int L = nt * 12288 + r * 192 + ((((k >> 3) ^ (r & 7)) << 3) | (k & 7));
        wq_sw[L] = f2bf(qkv_w[i]);
    } else {
        int j = i - 576 * 192;
        if (j < 192 * 192) {
            int r = j / 192, k = j % 192;
            int L = r * 192 + ((((k >> 3) ^ (r & 7)) << 3) | (k & 7));
            wp_sw[L] = f2bf(proj_w[j]);
        }
    }
}

// cpb MLP: 507 entries, 3 -> 512 relu -> 6
__global__ __launch_bounds__(64) void k_tbl(const float* tab, const float* w1, const float* b1,
                                            const float* w2, float* tbl) {
    int e = blockIdx.x;
    int t = threadIdx.x;
    float c0 = tab[e * 3 + 0], c1 = tab[e * 3 + 1], c2 = tab[e * 3 + 2];
    float acc[6] = {0.f, 0.f, 0.f, 0.f, 0.f, 0.f};
    for (int u = t; u < 512; u += 64) {
        float hv = c0 * w1[u * 3 + 0] + c1 * w1[u * 3 + 1] + c2 * w1[u * 3 + 2] + b1[u];
        hv = fmaxf(hv, 0.f);
        #pragma unroll
        for (int hh = 0; hh < 6; ++hh) acc[hh] += hv * w2[hh * 512 + u];
    }
    #pragma unroll
    for (int hh = 0; hh < 6; ++hh) {
        float v = acc[hh];
        for (int off = 32; off > 0; off >>= 1) v += __shfl_xor(v, off, 64);
        if (t == 0) tbl[e * 6 + hh] = v;
    }
}

// bm[w][h][q][k112] = 16*sigmoid(cpb) + mask (fp32), -60000 for k>=98
__global__ __launch_bounds__(256) void k_bm(const float* tbl, const int* rpi, const float* mask,
                                            float* bm) {
    int i = blockIdx.x * 256 + threadIdx.x;
    if (i >= 64 * 6 * 98 * 112) return;
    int k = i % 112;
    int q = (i / 112) % 98;
    int h = (i / (112 * 98)) % 6;
    int w = i / (112 * 98 * 6);
    float v;
    if (k < 98) {
        float t = tbl[rpi[q * 98 + k] * 6 + h];
        v = 16.f / (1.f + expf(-t)) + mask[(w * 98 + q) * 98 + k];
    } else v = -60000.f;
    bm[i] = v;
}

// ---------------- fully fused kernel: one block per window, 14 waves ----------------
// LDS (shorts): Qs[112][192]@0, Ks[112][192]@21504, VT 6x[32][128]@43008 (ao
// overlay 6x[112][32]), Bs[64][192]@67584.  XOR chunk swizzle: chunk^=(row&7).
// Wave (rg,hf): rg=wv>>1 owns rows rg*16..+16; hf=wv&1 splits cols/heads.
// Weight staging is LINEAR (images pre-swizzled by k_wcvt); read side unchanged.
__global__ __launch_bounds__(896) void k_fused(const float* x, const short* wq, const float* qkv_b,
                                               const float* lsc, const short* wp, const float* proj_b,
                                               const float* bm, float* outp) {
    __shared__ short lds[79872];
    short* Qs = lds;
    short* Ks = lds + 21504;
    short* VT = lds + 43008;
    short* Bs = lds + 67584;

    const int tid = threadIdx.x;
    const int wv = tid >> 6;
    const int lane = tid & 63;
    const int l16 = lane & 15, q4 = lane >> 4;
    const int rg = wv >> 1;
    const int hf = wv & 1;
    const int b = blockIdx.x;
    const int w = b & 63;
    const f32x4 zz = {0.f, 0.f, 0.f, 0.f};

    // zero VT (incl. token pad 98..127)
    {
        short8 z = {0, 0, 0, 0, 0, 0, 0, 0};
        #pragma unroll
        for (int it = 0; it < 4; ++it) {
            int c = tid + it * 896;
            if (c < 3072) *(short8*)&VT[c * 8] = z;
        }
    }
    // x A-frags: 16 rows per row-group, K=192, fp32->bf16 in-register
    short8 af[6];
    {
        int arow = rg * 16 + l16; if (arow > 97) arow = 97;
        const float* xp = x + ((size_t)b * 98 + arow) * 192 + q4 * 8;
        #pragma unroll
        for (int ks = 0; ks < 6; ++ks) {
            float4 f0 = *(const float4*)(xp + ks * 32);
            float4 f1 = *(const float4*)(xp + ks * 32 + 4);
            union { int i4[4]; short8 s; } u;
            asm("v_cvt_pk_bf16_f32 %0, %1, %2" : "=v"(u.i4[0]) : "v"(f0.x), "v"(f0.y));
            asm("v_cvt_pk_bf16_f32 %0, %1, %2" : "=v"(u.i4[1]) : "v"(f0.z), "v"(f0.w));
            asm("v_cvt_pk_bf16_f32 %0, %1, %2" : "=v"(u.i4[2]) : "v"(f1.x), "v"(f1.y));
            asm("v_cvt_pk_bf16_f32 %0, %1, %2" : "=v"(u.i4[3]) : "v"(f1.z), "v"(f1.w));
            af[ks] = u.s;
        }
    }
    // prologue: stage B tile 0 (1536 short8 chunks over 896 threads), LINEAR copy
    short8 t0, t1;
    {
        t0 = *(const short8*)(wq + tid * 8);
        if (tid < 640) t1 = *(const short8*)(wq + (tid + 896) * 8);
    }
    __syncthreads();   // VT zeros visible before any VT write
    {
        *(short8*)&Bs[tid * 8] = t0;
        if (tid < 640) *(short8*)&Bs[(tid + 896) * 8] = t1;
    }
    __syncthreads();

    const int row_w = rg * 16 + q4 * 4;
    // ---- qkv GEMM: 9 col-tiles of 64; wave does 16 rows x 32 cols (hf half) ----
    #pragma unroll 1
    for (int nt = 0; nt < 9; ++nt) {
        if (nt < 8) {   // T14: issue next tile's loads before compute (linear image copy)
            const short* wn = wq + (nt + 1) * 12288;
            t0 = *(const short8*)(wn + tid * 8);
            if (tid < 640) t1 = *(const short8*)(wn + (tid + 896) * 8);
        }
        f32x4 acc[2] = {zz, zz};
        #pragma unroll
        for (int ks = 0; ks < 6; ++ks)
            #pragma unroll
            for (int cf = 0; cf < 2; ++cf) {
                short8 bf = *(const short8*)&Bs[((hf * 2 + cf) * 16 + l16) * 192 +
                                                (((ks * 4 + q4) ^ (l16 & 7)) << 3)];
                acc[cf] = MFMA16(af[ks], bf, acc[cf]);
            }
        {
            int slot = nt * 2 + hf;
            int which = slot / 6;
            int h = slot - which * 6;
            float bia0 = qkv_b[slot * 32 + l16];
            float bia1 = qkv_b[slot * 32 + 16 + l16];
            float sc = 1.0f;
            if (which == 0) sc = __expf(fminf(lsc[h], LN100));
            #pragma unroll
            for (int i = 0; i < 4; ++i) {
                float v0 = acc[0][i] + bia0;
                float v1 = acc[1][i] + bia1;
                if (which < 2) {
                    float ss = v0 * v0 + v1 * v1;
                    ss += __shfl_xor(ss, 1, 16);
                    ss += __shfl_xor(ss, 2, 16);
                    ss += __shfl_xor(ss, 4, 16);
                    ss += __shfl_xor(ss, 8, 16);
                    float rn = sc / fmaxf(sqrtf(ss), 1e-12f);
                    v0 *= rn; v1 *= rn;
                }
                int row = row_w + i;
                if (which == 2) {
                    int swz = (((row >> 3) ^ (l16 & 7)) << 3) + (row & 7);
                    VT[h * 4096 + l16 * 128 + swz]        = f2bf(v0);
                    VT[h * 4096 + (l16 + 16) * 128 + swz] = f2bf(v1);
                } else {
                    short* T = (which == 0) ? Qs : Ks;
                    int c0i = h * 32 + l16, c1i = c0i + 16;
                    T[row * 192 + (((c0i >> 3) ^ (row & 7)) << 3) + (c0i & 7)] = f2bf(v0);
                    T[row * 192 + (((c1i >> 3) ^ (row & 7)) << 3) + (c1i & 7)] = f2bf(v1);
                }
            }
        }
        __syncthreads();
        if (nt < 8) {
            *(short8*)&Bs[tid * 8] = t0;
            if (tid < 640) *(short8*)&Bs[(tid + 896) * 8] = t1;
            __syncthreads();
        }
    }

    // ---- attention: 3 heads per wave (hf*3 .. hf*3+2), 16 q-rows ----
    const int rq = rg * 16 + l16;
    const int qc = rq < 98 ? rq : 97;
    const int srcA = ((q4 & 1) * 2) * 16 + l16;
    const int srcB = srcA + 16;
    const bool hi = (q4 & 2) != 0;

    #pragma unroll 1
    for (int j = 0; j < 3; ++j) {
        const int h = hf * 3 + j;
        const float* bmp = bm + (((size_t)w * 6 + h) * 98 + qc) * 112;
        f32x4 bh[7];
        #pragma unroll
        for (int ct = 0; ct < 7; ++ct) bh[ct] = *(const f32x4*)(bmp + ct * 16 + q4 * 4);
        short8 qf = *(const short8*)&Qs[rq * 192 + (((h * 4 + q4) ^ (l16 & 7)) << 3)];
        f32x4 cc[7];
        #pragma unroll
        for (int ct = 0; ct < 7; ++ct) {
            int rk = ct * 16 + l16;
            short8 kf = *(const short8*)&Ks[rk * 192 + (((h * 4 + q4) ^ (l16 & 7)) << 3)];
            cc[ct] = MFMA16(kf, qf, zz);
        }
        float mx = -1e30f;
        #pragma unroll
        for (int ct = 0; ct < 7; ++ct)
            #pragma unroll
            for (int i = 0; i < 4; ++i) {
                float s = cc[ct][i] + bh[ct][i];
                cc[ct][i] = s;
                mx = fmaxf(mx, s);
            }
        mx = fmaxf(mx, __shfl_xor(mx, 16, 64));
        mx = fmaxf(mx, __shfl_xor(mx, 32, 64));
        float sm = 0.f;
        #pragma unroll
        for (int ct = 0; ct < 7; ++ct)
            #pragma unroll
            for (int i = 0; i < 4; ++i) {
                float e = __expf(cc[ct][i] - mx);
                cc[ct][i] = e;
                sm += e;
            }
        sm += __shfl_xor(sm, 16, 64);
        sm += __shfl_xor(sm, 32, 64);
        float ri = 1.f / sm;
        int W[8][2];
        W[7][0] = 0; W[7][1] = 0;
        #pragma unroll
        for (int ct = 0; ct < 7; ++ct) {
            float a0 = cc[ct][0] * ri, a1 = cc[ct][1] * ri;
            float a2 = cc[ct][2] * ri, a3 = cc[ct][3] * ri;
            asm("v_cvt_pk_bf16_f32 %0, %1, %2" : "=v"(W[ct][0]) : "v"(a0), "v"(a1));
            asm("v_cvt_pk_bf16_f32 %0, %1, %2" : "=v"(W[ct][1]) : "v"(a2), "v"(a3));
        }
        f32x4 o0 = zz, o1 = zz;
        #pragma unroll
        for (int km = 0; km < 4; ++km) {
            int A0 = __shfl(W[2 * km][0], srcA, 64), B0 = __shfl(W[2 * km + 1][0], srcA, 64);
            int A1 = __shfl(W[2 * km][1], srcA, 64), B1 = __shfl(W[2 * km + 1][1], srcA, 64);
            int A2 = __shfl(W[2 * km][0], srcB, 64), B2 = __shfl(W[2 * km + 1][0], srcB, 64);
            int A3 = __shfl(W[2 * km][1], srcB, 64), B3 = __shfl(W[2 * km + 1][1], srcB, 64);
            union { int i4[4]; short8 s; } ua;
            ua.i4[0] = hi ? B0 : A0;
            ua.i4[1] = hi ? B1 : A1;
            ua.i4[2] = hi ? B2 : A2;
            ua.i4[3] = hi ? B3 : A3;
            int sA = h * 4096 + l16 * 128 + (((km * 4 + q4) ^ (l16 & 7)) << 3);
            short8 bv0 = *(const short8*)&VT[sA];
            short8 bv1 = *(const short8*)&VT[sA + 2048];
            o0 = MFMA16(ua.s, bv0, o0);
            o1 = MFMA16(ua.s, bv1, o1);
        }
        __syncthreads();   // all PV_h reads of VT[h] done before ao overlay
        #pragma unroll
        for (int i = 0; i < 4; ++i) {
            int q = row_w + i;
            VT[h * 4096 + q * 32 + l16]      = f2bf(o0[i]);
            VT[h * 4096 + q * 32 + 16 + l16] = f2bf(o1[i]);
        }
    }

    // ---- proj: stage pw image (linear copy) into Qs/Ks region, A-frags from ao overlay ----
    {
        short8 pwst[6];
        #pragma unroll
        for (int it = 0; it < 6; ++it) {
            int c = tid + it * 896;
            if (c < 4608) pwst[it] = *(const short8*)(wp + c * 8);
        }
        #pragma unroll
        for (int it = 0; it < 6; ++it) {
            int c = tid + it * 896;
            if (c < 4608) *(short8*)&lds[c * 8] = pwst[it];
        }
    }
    __syncthreads();
    {
        short8 pa[6];
        #pragma unroll
        for (int ks = 0; ks < 6; ++ks)
            pa[ks] = *(const short8*)&VT[ks * 4096 + rq * 32 + q4 * 8];
        f32x4 pacc[6] = {zz, zz, zz, zz, zz, zz};
        #pragma unroll
        for (int ks = 0; ks < 6; ++ks)
            #pragma unroll
            for (int cf = 0; cf < 6; ++cf) {
                short8 bf = *(const short8*)&lds[((hf * 6 + cf) * 16 + l16) * 192 +
                                                 (((ks * 4 + q4) ^ (l16 & 7)) << 3)];
                pacc[cf] = MFMA16(pa[ks], bf, pacc[cf]);
            }
        #pragma unroll
        for (int cf = 0; cf < 6; ++cf) {
            int cg = (hf * 6 + cf) * 16 + l16;
            float bia = proj_b[cg];
            #pragma unroll
            for (int i = 0; i < 4; ++i) {
                int q = row_w + i;
                if (q < 98)
                    outp[((size_t)b * 98 + q) * 192 + cg] = pacc[cf][i] + bia;
            }
        }
    }
}

extern "C" void kernel_launch(void* const* d_in, const int* in_sizes, int n_in,
                              void* d_out, int out_size, void* d_ws, size_t ws_size,
                              hipStream_t stream) {
    const float* x    = (const float*)d_in[0];
    const float* mask = (const float*)d_in[1];
    const float* qkvw = (const float*)d_in[2];
    const float* qkvb = (const float*)d_in[3];
    const float* lsc  = (const float*)d_in[4];
    const float* w1   = (const float*)d_in[5];
    const float* b1   = (const float*)d_in[6];
    const float* w2   = (const float*)d_in[7];
    const float* pw   = (const float*)d_in[8];
    const float* pb   = (const float*)d_in[9];
    const float* tab  = (const float*)d_in[10];
    const int*   rpi  = (const int*)d_in[11];

    char* ws = (char*)d_ws;
    short*  wq  = (short*)(ws + 0);          //    221,184 B (9 tile images)
    short*  wp  = (short*)(ws + 221184);     //     73,728 B (proj image)
    float*  tbl = (float*)(ws + 294912);     //     12,288 B
    float*  bm  = (float*)(ws + 307200);     // 16,859,136 B (fp32 bias+mask)
    float*  outp = (float*)d_out;

    k_wcvt<<<576, 256, 0, stream>>>(qkvw, pw, wq, wp);
    k_tbl<<<507, 64, 0, stream>>>(tab, w1, b1, w2, tbl);
    k_bm<<<16464, 256, 0, stream>>>(tbl, rpi, mask, bm);
    k_fused<<<2048, 896, 0, stream>>>(x, wq, qkvb, lsc, wp, pb, bm, outp);
}